// Round 2
// baseline (153.572 us; speedup 1.0000x reference)
//
#include <hip/hip_runtime.h>

// Problem constants
#define BB 8
#define HWSZ 65536             // 256*256
#define PLANE (3 * HWSZ)       // one batch's [3,H,W]
#define OUTSTRIDE (BB * PLANE) // one full output tensor [8,3,256,256]

// ---------------------------------------------------------------------------
// Fused projection: per-(k,b) block computes outs[k,b,:] = fc2(relu(fc1(feat)))
// Thread layout: t = s*48 + q, s = i-split (4), q = o-quad (48 -> 192 outputs).
// Weights read as float4 (row stride 192 floats = 48 float4), partials LDS-reduced.
__global__ __launch_bounds__(192) void k_proj(
    const float* __restrict__ f, const float* __restrict__ bf,
    const float* __restrict__ w1, const float* __restrict__ b1,
    const float* __restrict__ w2, const float* __restrict__ b2,
    float* __restrict__ outs) {
  int k = blockIdx.x >> 3, b = blockIdx.x & 7;
  int t = threadIdx.x, s = t / 48, q = t - s * 48;
  __shared__ float sf[512];
  __shared__ float red[4][192];
  __shared__ float sh[192];

  const float* feat = (k & 1) ? (bf + b * 512) : (f + b * 512);
  for (int i = t; i < 512; i += 192) sf[i] = feat[i];
  __syncthreads();

  // stage 1: 512 -> 192, relu
  {
    const float4* w = (const float4*)(w1 + (size_t)k * (512 * 192));
    float4 acc = {0.f, 0.f, 0.f, 0.f};
    int i0 = s * 128;
#pragma unroll 16
    for (int i = 0; i < 128; ++i) {
      float v = sf[i0 + i];
      float4 ww = w[(size_t)(i0 + i) * 48 + q];
      acc.x = fmaf(v, ww.x, acc.x); acc.y = fmaf(v, ww.y, acc.y);
      acc.z = fmaf(v, ww.z, acc.z); acc.w = fmaf(v, ww.w, acc.w);
    }
    ((float4*)red[s])[q] = acc;
  }
  __syncthreads();
  sh[t] = fmaxf(red[0][t] + red[1][t] + red[2][t] + red[3][t] + b1[k * 192 + t], 0.f);
  __syncthreads();

  // stage 2: 192 -> 192
  {
    const float4* w = (const float4*)(w2 + (size_t)k * (192 * 192));
    float4 acc = {0.f, 0.f, 0.f, 0.f};
    int i0 = s * 48;
#pragma unroll 16
    for (int i = 0; i < 48; ++i) {
      float v = sh[i0 + i];
      float4 ww = w[(size_t)(i0 + i) * 48 + q];
      acc.x = fmaf(v, ww.x, acc.x); acc.y = fmaf(v, ww.y, acc.y);
      acc.z = fmaf(v, ww.z, acc.z); acc.w = fmaf(v, ww.w, acc.w);
    }
    ((float4*)red[s])[q] = acc;
  }
  __syncthreads();
  outs[(k * 8 + b) * 192 + t] =
      red[0][t] + red[1][t] + red[2][t] + red[3][t] + b2[k * 192 + t];
}

// ---------------------------------------------------------------------------
// Fused final MLP: per-b block. cat = [outs0, outs1, outs2+outs3] (576),
// param[b,:] = fc2(relu(fc1(cat))). Same (s,q) layout.
__global__ __launch_bounds__(192) void k_fcat(
    const float* __restrict__ outs, const float* __restrict__ w1,
    const float* __restrict__ b1, const float* __restrict__ w2,
    const float* __restrict__ b2, float* __restrict__ param) {
  int b = blockIdx.x;
  int t = threadIdx.x, s = t / 48, q = t - s * 48;
  __shared__ float sc[576];
  __shared__ float red[4][192];
  __shared__ float sh[192];

  sc[t]       = outs[(0 * 8 + b) * 192 + t];
  sc[192 + t] = outs[(1 * 8 + b) * 192 + t];
  sc[384 + t] = outs[(2 * 8 + b) * 192 + t] + outs[(3 * 8 + b) * 192 + t];
  __syncthreads();

  // stage 1: 576 -> 192, relu
  {
    const float4* w = (const float4*)w1;
    float4 acc = {0.f, 0.f, 0.f, 0.f};
    int i0 = s * 144;
#pragma unroll 16
    for (int i = 0; i < 144; ++i) {
      float v = sc[i0 + i];
      float4 ww = w[(size_t)(i0 + i) * 48 + q];
      acc.x = fmaf(v, ww.x, acc.x); acc.y = fmaf(v, ww.y, acc.y);
      acc.z = fmaf(v, ww.z, acc.z); acc.w = fmaf(v, ww.w, acc.w);
    }
    ((float4*)red[s])[q] = acc;
  }
  __syncthreads();
  sh[t] = fmaxf(red[0][t] + red[1][t] + red[2][t] + red[3][t] + b1[t], 0.f);
  __syncthreads();

  // stage 2: 192 -> 192
  {
    const float4* w = (const float4*)w2;
    float4 acc = {0.f, 0.f, 0.f, 0.f};
    int i0 = s * 48;
#pragma unroll 16
    for (int i = 0; i < 48; ++i) {
      float v = sh[i0 + i];
      float4 ww = w[(size_t)(i0 + i) * 48 + q];
      acc.x = fmaf(v, ww.x, acc.x); acc.y = fmaf(v, ww.y, acc.y);
      acc.z = fmaf(v, ww.z, acc.z); acc.w = fmaf(v, ww.w, acc.w);
    }
    ((float4*)red[s])[q] = acc;
  }
  __syncthreads();
  param[b * 192 + t] = red[0][t] + red[1][t] + red[2][t] + red[3][t] + b2[t];
}

// ---------------------------------------------------------------------------
// Render: closed-form piecewise-linear curve eval.
// total(v) = S_k/64 + (v - k/64) * p_k,  k = floor(64 v);  out = total * 64/(S_64+eps)
__global__ __launch_bounds__(256) void k_render(
    const float* __restrict__ x, const float* __restrict__ p_all,
    const float* __restrict__ outs, float* __restrict__ out) {
  int b = blockIdx.y, tid = threadIdx.x;
  __shared__ float sp[9][64];
  __shared__ float sS[9][65];
  __shared__ float snorm[9];

  for (int idx = tid; idx < 576; idx += 256) {
    int cur = idx >> 6, i = idx & 63;
    int oi = cur / 3, c = cur - oi * 3;
    sp[cur][i] = (oi == 0) ? p_all[b * 192 + c * 64 + i]
                           : outs[((oi - 1) * 8 + b) * 192 + c * 64 + i];
  }
  __syncthreads();
  if (tid < 9) {
    float s = 0.f;
    sS[tid][0] = 0.f;
    for (int i = 0; i < 64; ++i) { s += sp[tid][i]; sS[tid][i + 1] = s; }
    snorm[tid] = 64.f / (s + 1e-30f);
  }
  __syncthreads();

  auto ev = [&](int cur, float v) -> float {
    int k = (int)(v * 64.f);
    k = k < 0 ? 0 : (k > 63 ? 63 : k);
    float t = v - (float)k * 0.015625f;
    return fmaf(sS[cur][k], 0.015625f, t * sp[cur][k]) * snorm[cur];
  };
  auto ev4 = [&](int cur, float4 v) -> float4 {
    float4 r;
    r.x = ev(cur, v.x); r.y = ev(cur, v.y);
    r.z = ev(cur, v.z); r.w = ev(cur, v.w);
    return r;
  };

  int s4 = blockIdx.x * 256 + tid;  // float4 index within one channel plane
  const float* xb = x + (size_t)b * PLANE;
  float4 vr = ((const float4*)(xb))[s4];
  float4 vg = ((const float4*)(xb + HWSZ))[s4];
  float4 vb = ((const float4*)(xb + 2 * HWSZ))[s4];

  float4 gr;
  gr.x = fmaf(0.299f, vr.x, fmaf(0.587f, vg.x, 0.114f * vb.x));
  gr.y = fmaf(0.299f, vr.y, fmaf(0.587f, vg.y, 0.114f * vb.y));
  gr.z = fmaf(0.299f, vr.z, fmaf(0.587f, vg.z, 0.114f * vb.z));
  gr.w = fmaf(0.299f, vr.w, fmaf(0.587f, vg.w, 0.114f * vb.w));

  float* o0 = out + (size_t)b * PLANE;
  float* o1 = out + OUTSTRIDE + (size_t)b * PLANE;
  float* o2 = out + 2 * OUTSTRIDE + (size_t)b * PLANE;

  ((float4*)(o0))[s4]            = ev4(0, vr);
  ((float4*)(o0 + HWSZ))[s4]     = ev4(1, vg);
  ((float4*)(o0 + 2 * HWSZ))[s4] = ev4(2, vb);
  ((float4*)(o1))[s4]            = ev4(3, gr);
  ((float4*)(o1 + HWSZ))[s4]     = ev4(4, gr);
  ((float4*)(o1 + 2 * HWSZ))[s4] = ev4(5, gr);
  ((float4*)(o2))[s4]            = ev4(6, gr);
  ((float4*)(o2 + HWSZ))[s4]     = ev4(7, gr);
  ((float4*)(o2 + 2 * HWSZ))[s4] = ev4(8, gr);
}

// ---------------------------------------------------------------------------
extern "C" void kernel_launch(void* const* d_in, const int* in_sizes, int n_in,
                              void* d_out, int out_size, void* d_ws, size_t ws_size,
                              hipStream_t stream) {
  const float* x   = (const float*)d_in[0];
  const float* f   = (const float*)d_in[1];
  const float* bf  = (const float*)d_in[2];
  const float* pw1 = (const float*)d_in[3];
  const float* pb1 = (const float*)d_in[4];
  const float* pw2 = (const float*)d_in[5];
  const float* pb2 = (const float*)d_in[6];
  const float* fw1 = (const float*)d_in[7];
  const float* fb1 = (const float*)d_in[8];
  const float* fw2 = (const float*)d_in[9];
  const float* fb2 = (const float*)d_in[10];
  float* out = (float*)d_out;
  float* ws  = (float*)d_ws;

  float* outs  = ws;         // [4,8,192] = 6144
  float* param = ws + 6144;  // [8,192]   = 1536

  k_proj<<<32, 192, 0, stream>>>(f, bf, pw1, pb1, pw2, pb2, outs);
  k_fcat<<<8, 192, 0, stream>>>(outs, fw1, fb1, fw2, fb2, param);
  dim3 grid(64, 8);
  k_render<<<grid, 256, 0, stream>>>(x, param, outs, out);
}

// Round 3
// 108.067 us; speedup vs baseline: 1.4211x; 1.4211x over previous
//
#include <hip/hip_runtime.h>

// Problem constants
#define BB 8
#define HWSZ 65536             // 256*256
#define PLANE (3 * HWSZ)       // one batch's [3,H,W]
#define OUTSTRIDE (BB * PLANE) // one full output tensor [8,3,256,256]

// ---------------------------------------------------------------------------
// Layer 1 of stacked projections: h[k,b,:] = relu(feat[k,b,:] @ W1[k] + b1[k])
// Grid: 48 = k(4) * o-tile(12, 16 outputs each). Block 256 = (s=16 i-splits) x (o=16).
// Thread holds 32 weights register-stationary (i = s + 16j), loops 8 batches from LDS.
__global__ __launch_bounds__(256) void k_gemm_proj1(
    const float* __restrict__ f, const float* __restrict__ bf,
    const float* __restrict__ w1, const float* __restrict__ b1,
    float* __restrict__ h) {
  int k = blockIdx.x / 12, ot = blockIdx.x - k * 12, ob = ot * 16;
  int t = threadIdx.x, o = t & 15, s = t >> 4;
  __shared__ float sf[8 * 512];
  __shared__ float red[16 * 128];
  const float* feat = (k & 1) ? bf : f;   // [8,512] contiguous
  for (int idx = t; idx < 4096; idx += 256) sf[idx] = feat[idx];
  const float* w = w1 + (size_t)k * (512 * 192) + ob + o;
  float wr[32];
#pragma unroll
  for (int j = 0; j < 32; ++j) wr[j] = w[(size_t)(s + 16 * j) * 192];
  __syncthreads();
  float acc[8];
#pragma unroll
  for (int b = 0; b < 8; ++b) {
    float a = 0.f;
    const float* sfb = sf + b * 512 + s;
#pragma unroll
    for (int j = 0; j < 32; ++j) a = fmaf(wr[j], sfb[16 * j], a);
    acc[b] = a;
  }
#pragma unroll
  for (int b = 0; b < 8; ++b) red[s * 128 + b * 16 + o] = acc[b];
  __syncthreads();
  if (t < 128) {
    float a = 0.f;
#pragma unroll
    for (int s2 = 0; s2 < 16; ++s2) a += red[s2 * 128 + t];
    int b = t >> 4, oo = t & 15;
    a += b1[k * 192 + ob + oo];
    h[(k * 8 + b) * 192 + ob + oo] = fmaxf(a, 0.f);
  }
}

// Layer 2: outs[k,b,:] = h[k,b,:] @ W2[k] + b2[k].  K=192, 16 splits of 12.
__global__ __launch_bounds__(256) void k_gemm_proj2(
    const float* __restrict__ h, const float* __restrict__ w2,
    const float* __restrict__ b2, float* __restrict__ outs) {
  int k = blockIdx.x / 12, ot = blockIdx.x - k * 12, ob = ot * 16;
  int t = threadIdx.x, o = t & 15, s = t >> 4;
  __shared__ float sh[8 * 192];
  __shared__ float red[16 * 128];
  for (int idx = t; idx < 1536; idx += 256) sh[idx] = h[k * 1536 + idx];
  const float* w = w2 + (size_t)k * (192 * 192) + ob + o;
  float wr[12];
#pragma unroll
  for (int j = 0; j < 12; ++j) wr[j] = w[(size_t)(s + 16 * j) * 192];
  __syncthreads();
  float acc[8];
#pragma unroll
  for (int b = 0; b < 8; ++b) {
    float a = 0.f;
    const float* shb = sh + b * 192 + s;
#pragma unroll
    for (int j = 0; j < 12; ++j) a = fmaf(wr[j], shb[16 * j], a);
    acc[b] = a;
  }
#pragma unroll
  for (int b = 0; b < 8; ++b) red[s * 128 + b * 16 + o] = acc[b];
  __syncthreads();
  if (t < 128) {
    float a = 0.f;
#pragma unroll
    for (int s2 = 0; s2 < 16; ++s2) a += red[s2 * 128 + t];
    int b = t >> 4, oo = t & 15;
    outs[(k * 8 + b) * 192 + ob + oo] = a + b2[k * 192 + ob + oo];
  }
}

// Final MLP layer 1: cat=[outs0, outs1, outs2+outs3] (576) -> relu(cat@W1+b1).
// Grid 24 = o-tile(8 outputs). Block 256 = (s=32 i-splits of 18) x (o=8).
__global__ __launch_bounds__(256) void k_gemm_fcat1(
    const float* __restrict__ outs, const float* __restrict__ w1,
    const float* __restrict__ bias, float* __restrict__ hc) {
  int ob = blockIdx.x * 8;
  int t = threadIdx.x, o = t & 7, s = t >> 3;
  __shared__ float sc[8 * 576];
  __shared__ float red[32 * 64];
  for (int idx = t; idx < 4608; idx += 256) {
    int b = idx / 576, i = idx - b * 576;
    float v;
    if (i < 192)      v = outs[(0 * 8 + b) * 192 + i];
    else if (i < 384) v = outs[(1 * 8 + b) * 192 + (i - 192)];
    else              v = outs[(2 * 8 + b) * 192 + (i - 384)] +
                          outs[(3 * 8 + b) * 192 + (i - 384)];
    sc[idx] = v;
  }
  const float* w = w1 + ob + o;
  float wr[18];
#pragma unroll
  for (int j = 0; j < 18; ++j) wr[j] = w[(size_t)(s + 32 * j) * 192];
  __syncthreads();
  float acc[8];
#pragma unroll
  for (int b = 0; b < 8; ++b) {
    float a = 0.f;
    const float* scb = sc + b * 576 + s;
#pragma unroll
    for (int j = 0; j < 18; ++j) a = fmaf(wr[j], scb[32 * j], a);
    acc[b] = a;
  }
#pragma unroll
  for (int b = 0; b < 8; ++b) red[s * 64 + b * 8 + o] = acc[b];
  __syncthreads();
  if (t < 64) {
    float a = 0.f;
#pragma unroll
    for (int s2 = 0; s2 < 32; ++s2) a += red[s2 * 64 + t];
    int b = t >> 3, oo = t & 7;
    a += bias[ob + oo];
    hc[b * 192 + ob + oo] = fmaxf(a, 0.f);
  }
}

// Final MLP layer 2: param = hc@W2 + b2.  K=192, 32 splits of 6, o-tile 8.
__global__ __launch_bounds__(256) void k_gemm_fcat2(
    const float* __restrict__ hc, const float* __restrict__ w2,
    const float* __restrict__ bias, float* __restrict__ param) {
  int ob = blockIdx.x * 8;
  int t = threadIdx.x, o = t & 7, s = t >> 3;
  __shared__ float sh[8 * 192];
  __shared__ float red[32 * 64];
  for (int idx = t; idx < 1536; idx += 256) sh[idx] = hc[idx];
  const float* w = w2 + ob + o;
  float wr[6];
#pragma unroll
  for (int j = 0; j < 6; ++j) wr[j] = w[(size_t)(s + 32 * j) * 192];
  __syncthreads();
  float acc[8];
#pragma unroll
  for (int b = 0; b < 8; ++b) {
    float a = 0.f;
    const float* shb = sh + b * 192 + s;
#pragma unroll
    for (int j = 0; j < 6; ++j) a = fmaf(wr[j], shb[32 * j], a);
    acc[b] = a;
  }
#pragma unroll
  for (int b = 0; b < 8; ++b) red[s * 64 + b * 8 + o] = acc[b];
  __syncthreads();
  if (t < 64) {
    float a = 0.f;
#pragma unroll
    for (int s2 = 0; s2 < 32; ++s2) a += red[s2 * 64 + t];
    int b = t >> 3, oo = t & 7;
    param[b * 192 + ob + oo] = a + bias[ob + oo];
  }
}

// ---------------------------------------------------------------------------
// Render: closed-form piecewise-linear curve eval.
// total(v) = S_k/64 + (v - k/64) * p_k,  k = floor(64 v);  out = total * 64/(S_64+eps)
__global__ __launch_bounds__(256) void k_render(
    const float* __restrict__ x, const float* __restrict__ p_all,
    const float* __restrict__ outs, float* __restrict__ out) {
  int b = blockIdx.y, tid = threadIdx.x;
  __shared__ float sp[9][64];
  __shared__ float sS[9][65];
  __shared__ float snorm[9];

  for (int idx = tid; idx < 576; idx += 256) {
    int cur = idx >> 6, i = idx & 63;
    int oi = cur / 3, c = cur - oi * 3;
    sp[cur][i] = (oi == 0) ? p_all[b * 192 + c * 64 + i]
                           : outs[((oi - 1) * 8 + b) * 192 + c * 64 + i];
  }
  __syncthreads();
  if (tid < 9) {
    float s = 0.f;
    sS[tid][0] = 0.f;
    for (int i = 0; i < 64; ++i) { s += sp[tid][i]; sS[tid][i + 1] = s; }
    snorm[tid] = 64.f / (s + 1e-30f);
  }
  __syncthreads();

  auto ev = [&](int cur, float v) -> float {
    int k = (int)(v * 64.f);
    k = k < 0 ? 0 : (k > 63 ? 63 : k);
    float t = v - (float)k * 0.015625f;
    return fmaf(sS[cur][k], 0.015625f, t * sp[cur][k]) * snorm[cur];
  };
  auto ev4 = [&](int cur, float4 v) -> float4 {
    float4 r;
    r.x = ev(cur, v.x); r.y = ev(cur, v.y);
    r.z = ev(cur, v.z); r.w = ev(cur, v.w);
    return r;
  };

  int s4 = blockIdx.x * 256 + tid;
  const float* xb = x + (size_t)b * PLANE;
  float4 vr = ((const float4*)(xb))[s4];
  float4 vg = ((const float4*)(xb + HWSZ))[s4];
  float4 vb = ((const float4*)(xb + 2 * HWSZ))[s4];

  float4 gr;
  gr.x = fmaf(0.299f, vr.x, fmaf(0.587f, vg.x, 0.114f * vb.x));
  gr.y = fmaf(0.299f, vr.y, fmaf(0.587f, vg.y, 0.114f * vb.y));
  gr.z = fmaf(0.299f, vr.z, fmaf(0.587f, vg.z, 0.114f * vb.z));
  gr.w = fmaf(0.299f, vr.w, fmaf(0.587f, vg.w, 0.114f * vb.w));

  float* o0 = out + (size_t)b * PLANE;
  float* o1 = out + OUTSTRIDE + (size_t)b * PLANE;
  float* o2 = out + 2 * OUTSTRIDE + (size_t)b * PLANE;

  ((float4*)(o0))[s4]            = ev4(0, vr);
  ((float4*)(o0 + HWSZ))[s4]     = ev4(1, vg);
  ((float4*)(o0 + 2 * HWSZ))[s4] = ev4(2, vb);
  ((float4*)(o1))[s4]            = ev4(3, gr);
  ((float4*)(o1 + HWSZ))[s4]     = ev4(4, gr);
  ((float4*)(o1 + 2 * HWSZ))[s4] = ev4(5, gr);
  ((float4*)(o2))[s4]            = ev4(6, gr);
  ((float4*)(o2 + HWSZ))[s4]     = ev4(7, gr);
  ((float4*)(o2 + 2 * HWSZ))[s4] = ev4(8, gr);
}

// ---------------------------------------------------------------------------
extern "C" void kernel_launch(void* const* d_in, const int* in_sizes, int n_in,
                              void* d_out, int out_size, void* d_ws, size_t ws_size,
                              hipStream_t stream) {
  const float* x   = (const float*)d_in[0];
  const float* f   = (const float*)d_in[1];
  const float* bf  = (const float*)d_in[2];
  const float* pw1 = (const float*)d_in[3];
  const float* pb1 = (const float*)d_in[4];
  const float* pw2 = (const float*)d_in[5];
  const float* pb2 = (const float*)d_in[6];
  const float* fw1 = (const float*)d_in[7];
  const float* fb1 = (const float*)d_in[8];
  const float* fw2 = (const float*)d_in[9];
  const float* fb2 = (const float*)d_in[10];
  float* out = (float*)d_out;
  float* ws  = (float*)d_ws;

  float* h     = ws;          // [4,8,192] = 6144
  float* outs  = ws + 6144;   // [4,8,192] = 6144
  float* hc    = ws + 12288;  // [8,192]   = 1536
  float* param = ws + 13824;  // [8,192]   = 1536

  k_gemm_proj1<<<48, 256, 0, stream>>>(f, bf, pw1, pb1, h);
  k_gemm_proj2<<<48, 256, 0, stream>>>(h, pw2, pb2, outs);
  k_gemm_fcat1<<<24, 256, 0, stream>>>(outs, fw1, fb1, hc);
  k_gemm_fcat2<<<24, 256, 0, stream>>>(hc, fw2, fb2, param);
  dim3 grid(64, 8);
  k_render<<<grid, 256, 0, stream>>>(x, param, outs, out);
}